// Round 1
// baseline (1599.173 us; speedup 1.0000x reference)
//
#include <hip/hip_runtime.h>

#define NN 50000
#define NE 800000
#define D 128

// Transpose the six 128x128 weight matrices: Wt[k][c] = W[c][k]
__global__ __launch_bounds__(256) void transpose6(
    const float* __restrict__ s0, const float* __restrict__ s1,
    const float* __restrict__ s2, const float* __restrict__ s3,
    const float* __restrict__ s4, const float* __restrict__ s5,
    float* __restrict__ d0, float* __restrict__ d1, float* __restrict__ d2,
    float* __restrict__ d3, float* __restrict__ d4, float* __restrict__ d5) {
    const float* srcs[6] = {s0, s1, s2, s3, s4, s5};
    float* dsts[6] = {d0, d1, d2, d3, d4, d5};
    int m = blockIdx.y;
    const float* src = srcs[m];
    float* dst = dsts[m];
    int idx = blockIdx.x * 256 + threadIdx.x;
    int c = idx >> 7, k = idx & 127;
    dst[k * D + c] = src[c * D + k];
}

// out[n][c] (+)= scale_n * dot(A[n,:], W[c,:]) + bias[c], optional relu.
// Wt is W transposed: Wt[k*128 + c] = W[c][k].
// Thread: c = tid&127 (one column), 16 rows each; block covers 32 rows.
__global__ __launch_bounds__(256)
void gemm128(const float* __restrict__ A, const float* __restrict__ Wt,
             const float* __restrict__ bias, const int* __restrict__ cnt,
             float* __restrict__ out, int do_acc, int do_relu) {
    const int c = threadIdx.x & 127;
    const int rh = threadIdx.x >> 7;
    const int n0 = blockIdx.x * 32 + rh * 16;

    int rowoff[16];
#pragma unroll
    for (int r = 0; r < 16; ++r) {
        int row = n0 + r;
        if (row > NN - 1) row = NN - 1;  // clamp loads; stores guarded below
        rowoff[r] = row * D;
    }
    float acc[16];
#pragma unroll
    for (int r = 0; r < 16; ++r) acc[r] = 0.0f;

    for (int k = 0; k < D; k += 4) {
        const float w0 = Wt[(k + 0) * D + c];
        const float w1 = Wt[(k + 1) * D + c];
        const float w2 = Wt[(k + 2) * D + c];
        const float w3 = Wt[(k + 3) * D + c];
#pragma unroll
        for (int r = 0; r < 16; ++r) {
            const float4 xv = *(const float4*)&A[rowoff[r] + k];
            acc[r] += xv.x * w0 + xv.y * w1 + xv.z * w2 + xv.w * w3;
        }
    }

#pragma unroll
    for (int r = 0; r < 16; ++r) {
        const int row = n0 + r;
        if (row < NN) {
            float v = acc[r];
            if (cnt) {
                int cc = cnt[row];
                v *= 1.0f / (float)(cc > 1 ? cc : 1);
            }
            if (bias) v += bias[c];
            if (do_acc) v += out[row * D + c];
            if (do_relu) v = v > 0.0f ? v : 0.0f;
            out[row * D + c] = v;
        }
    }
}

// agg[dst] += h[src] per edge; cnt[dst] += 1. 2 edges per 256-thread block.
__global__ __launch_bounds__(256)
void scatter_add(const float* __restrict__ h, const int* __restrict__ ei,
                 float* __restrict__ agg, int* __restrict__ cnt) {
    const int e = blockIdx.x * 2 + (threadIdx.x >> 7);
    const int f = threadIdx.x & 127;
    const int src = ei[e];
    const int dst = ei[NE + e];
    atomicAdd(&agg[dst * D + f], h[src * D + f]);
    if (f == 0) atomicAdd(&cnt[dst], 1);
}

extern "C" void kernel_launch(void* const* d_in, const int* in_sizes, int n_in,
                              void* d_out, int out_size, void* d_ws, size_t ws_size,
                              hipStream_t stream) {
    const float* x   = (const float*)d_in[0];
    const int*   ei  = (const int*)d_in[1];
    const float* Wp1 = (const float*)d_in[2];
    const float* bp1 = (const float*)d_in[3];
    const float* Wl1 = (const float*)d_in[4];
    const float* bl1 = (const float*)d_in[5];
    const float* Wr1 = (const float*)d_in[6];
    const float* Wp2 = (const float*)d_in[7];
    const float* bp2 = (const float*)d_in[8];
    const float* Wl2 = (const float*)d_in[9];
    const float* bl2 = (const float*)d_in[10];
    const float* Wr2 = (const float*)d_in[11];
    float* out = (float*)d_out;

    char* ws = (char*)d_ws;
    size_t off = 0;
    auto alloc = [&](size_t bytes) {
        void* p = ws + off;
        off += (bytes + 511) & ~511ull;
        return p;
    };
    float* Wt[6];
    for (int i = 0; i < 6; ++i) Wt[i] = (float*)alloc((size_t)D * D * 4);
    float* bufA   = (float*)alloc((size_t)NN * D * 4);  // h1, then h2
    float* bufAgg = (float*)alloc((size_t)NN * D * 4);
    float* bufH   = (float*)alloc((size_t)NN * D * 4);  // layer-1 output h
    int*   cnt    = (int*)alloc((size_t)NN * 4);

    transpose6<<<dim3(64, 6), 256, 0, stream>>>(Wp1, Wl1, Wr1, Wp2, Wl2, Wr2,
                                                Wt[0], Wt[1], Wt[2], Wt[3], Wt[4], Wt[5]);

    const int GB = (NN + 31) / 32;  // 1563 blocks

    // ---- layer 1 ----
    gemm128<<<GB, 256, 0, stream>>>(x, Wt[0], bp1, nullptr, bufA, 0, 1);   // h1 = relu(x@Wp1.T+bp1)
    hipMemsetAsync(bufAgg, 0, (size_t)NN * D * 4, stream);
    hipMemsetAsync(cnt, 0, (size_t)NN * 4, stream);
    scatter_add<<<NE / 2, 256, 0, stream>>>(bufA, ei, bufAgg, cnt);
    gemm128<<<GB, 256, 0, stream>>>(bufAgg, Wt[1], bl1, cnt, bufH, 0, 0);  // z = mean@Wl1.T+bl1
    gemm128<<<GB, 256, 0, stream>>>(x, Wt[2], nullptr, nullptr, bufH, 1, 1);  // h = relu(z + x@Wr1.T)

    // ---- layer 2 ----
    gemm128<<<GB, 256, 0, stream>>>(bufH, Wt[3], bp2, nullptr, bufA, 0, 1);  // h2 = relu(h@Wp2.T+bp2)
    hipMemsetAsync(bufAgg, 0, (size_t)NN * D * 4, stream);
    hipMemsetAsync(cnt, 0, (size_t)NN * 4, stream);
    scatter_add<<<NE / 2, 256, 0, stream>>>(bufA, ei, bufAgg, cnt);
    gemm128<<<GB, 256, 0, stream>>>(bufAgg, Wt[4], bl2, cnt, out, 0, 0);   // out = mean@Wl2.T+bl2
    gemm128<<<GB, 256, 0, stream>>>(bufH, Wt[5], nullptr, nullptr, out, 1, 0);  // out += h@Wr2.T
}

// Round 2
// 1106.304 us; speedup vs baseline: 1.4455x; 1.4455x over previous
//
#include <hip/hip_runtime.h>

#define NN 50000
#define NE 800000
#define D 128
#define SCAN_BLOCKS 196  // ceil(50000/256)

// Transpose the six 128x128 weight matrices: Wt[k][c] = W[c][k]
__global__ __launch_bounds__(256) void transpose6(
    const float* __restrict__ s0, const float* __restrict__ s1,
    const float* __restrict__ s2, const float* __restrict__ s3,
    const float* __restrict__ s4, const float* __restrict__ s5,
    float* __restrict__ d0, float* __restrict__ d1, float* __restrict__ d2,
    float* __restrict__ d3, float* __restrict__ d4, float* __restrict__ d5) {
    const float* srcs[6] = {s0, s1, s2, s3, s4, s5};
    float* dsts[6] = {d0, d1, d2, d3, d4, d5};
    int m = blockIdx.y;
    const float* src = srcs[m];
    float* dst = dsts[m];
    int idx = blockIdx.x * 256 + threadIdx.x;
    int c = idx >> 7, k = idx & 127;
    dst[k * D + c] = src[c * D + k];
}

// ---------------- CSR build ----------------

__global__ __launch_bounds__(256)
void histogram(const int* __restrict__ ei, int* __restrict__ cnt) {
    int e = blockIdx.x * 256 + threadIdx.x;
    atomicAdd(&cnt[ei[NE + e]], 1);
}

// per-block exclusive scan of cnt -> row_start (partial), block sums -> bsum
__global__ __launch_bounds__(256)
void scan_block(const int* __restrict__ cnt, int* __restrict__ row_start,
                int* __restrict__ bsum) {
    __shared__ int tmp[256];
    int i = blockIdx.x * 256 + threadIdx.x;
    int v = (i < NN) ? cnt[i] : 0;
    tmp[threadIdx.x] = v;
    __syncthreads();
    for (int off = 1; off < 256; off <<= 1) {
        int t = (threadIdx.x >= off) ? tmp[threadIdx.x - off] : 0;
        __syncthreads();
        tmp[threadIdx.x] += t;
        __syncthreads();
    }
    if (i < NN) row_start[i] = tmp[threadIdx.x] - v;  // exclusive
    if (threadIdx.x == 255) bsum[blockIdx.x] = tmp[255];
}

// single-block exclusive scan of bsum (SCAN_BLOCKS <= 256) in place
__global__ __launch_bounds__(256)
void scan_sums(int* __restrict__ bsum) {
    __shared__ int tmp[256];
    int v = (threadIdx.x < SCAN_BLOCKS) ? bsum[threadIdx.x] : 0;
    tmp[threadIdx.x] = v;
    __syncthreads();
    for (int off = 1; off < 256; off <<= 1) {
        int t = (threadIdx.x >= off) ? tmp[threadIdx.x - off] : 0;
        __syncthreads();
        tmp[threadIdx.x] += t;
        __syncthreads();
    }
    if (threadIdx.x < SCAN_BLOCKS) bsum[threadIdx.x] = tmp[threadIdx.x] - v;
}

// row_start[i] += bsum[block]; cursor[i] = row_start[i]; row_start[NN] = NE
__global__ __launch_bounds__(256)
void add_offsets(int* __restrict__ row_start, const int* __restrict__ bsum,
                 int* __restrict__ cursor) {
    int i = blockIdx.x * 256 + threadIdx.x;
    if (i < NN) {
        int v = row_start[i] + bsum[blockIdx.x];
        row_start[i] = v;
        cursor[i] = v;
    } else if (i == NN) {
        row_start[NN] = NE;
    }
}

__global__ __launch_bounds__(256)
void fill_csr(const int* __restrict__ ei, int* __restrict__ cursor,
              int* __restrict__ src_sorted) {
    int e = blockIdx.x * 256 + threadIdx.x;
    int src = ei[e];
    int dst = ei[NE + e];
    int pos = atomicAdd(&cursor[dst], 1);
    src_sorted[pos] = src;
}

// ---------------- aggregation: one wave per dst node ----------------
// agg[n][:] = mean over neighbors src of h[src][:]  (float2 per lane, 64 lanes)
__global__ __launch_bounds__(256)
void gather_mean(const float* __restrict__ h, const int* __restrict__ row_start,
                 const int* __restrict__ src_sorted, float* __restrict__ agg) {
    const int n = blockIdx.x * 4 + (threadIdx.x >> 6);
    const int f = threadIdx.x & 63;
    const int b = row_start[n];
    const int e = row_start[n + 1];
    const float2* h2 = (const float2*)h;
    float sx = 0.0f, sy = 0.0f;
    for (int i = b; i < e; ++i) {
        const int s = src_sorted[i];
        const float2 v = h2[s * 64 + f];
        sx += v.x;
        sy += v.y;
    }
    const int deg = e - b;
    const float inv = 1.0f / (float)(deg > 0 ? deg : 1);
    ((float2*)agg)[n * 64 + f] = make_float2(sx * inv, sy * inv);
}

// ---------------- dense GEMM (f32 VALU) ----------------
// out[n][c] (+)= dot(A[n,:], W[c,:]) + bias[c], optional relu.
// Wt[k*128 + c] = W[c][k].
__global__ __launch_bounds__(256)
void gemm128(const float* __restrict__ A, const float* __restrict__ Wt,
             const float* __restrict__ bias, float* __restrict__ out,
             int do_acc, int do_relu) {
    const int c = threadIdx.x & 127;
    const int rh = threadIdx.x >> 7;
    const int n0 = blockIdx.x * 32 + rh * 16;

    int rowoff[16];
#pragma unroll
    for (int r = 0; r < 16; ++r) {
        int row = n0 + r;
        if (row > NN - 1) row = NN - 1;
        rowoff[r] = row * D;
    }
    float acc[16];
#pragma unroll
    for (int r = 0; r < 16; ++r) acc[r] = 0.0f;

    for (int k = 0; k < D; k += 4) {
        const float w0 = Wt[(k + 0) * D + c];
        const float w1 = Wt[(k + 1) * D + c];
        const float w2 = Wt[(k + 2) * D + c];
        const float w3 = Wt[(k + 3) * D + c];
#pragma unroll
        for (int r = 0; r < 16; ++r) {
            const float4 xv = *(const float4*)&A[rowoff[r] + k];
            acc[r] += xv.x * w0 + xv.y * w1 + xv.z * w2 + xv.w * w3;
        }
    }

#pragma unroll
    for (int r = 0; r < 16; ++r) {
        const int row = n0 + r;
        if (row < NN) {
            float v = acc[r];
            if (bias) v += bias[c];
            if (do_acc) v += out[row * D + c];
            if (do_relu) v = v > 0.0f ? v : 0.0f;
            out[row * D + c] = v;
        }
    }
}

extern "C" void kernel_launch(void* const* d_in, const int* in_sizes, int n_in,
                              void* d_out, int out_size, void* d_ws, size_t ws_size,
                              hipStream_t stream) {
    const float* x   = (const float*)d_in[0];
    const int*   ei  = (const int*)d_in[1];
    const float* Wp1 = (const float*)d_in[2];
    const float* bp1 = (const float*)d_in[3];
    const float* Wl1 = (const float*)d_in[4];
    const float* bl1 = (const float*)d_in[5];
    const float* Wr1 = (const float*)d_in[6];
    const float* Wp2 = (const float*)d_in[7];
    const float* bp2 = (const float*)d_in[8];
    const float* Wl2 = (const float*)d_in[9];
    const float* bl2 = (const float*)d_in[10];
    const float* Wr2 = (const float*)d_in[11];
    float* out = (float*)d_out;

    char* ws = (char*)d_ws;
    size_t off = 0;
    auto alloc = [&](size_t bytes) {
        void* p = ws + off;
        off += (bytes + 511) & ~511ull;
        return p;
    };
    float* Wt[6];
    for (int i = 0; i < 6; ++i) Wt[i] = (float*)alloc((size_t)D * D * 4);
    float* bufA    = (float*)alloc((size_t)NN * D * 4);  // h1 / h2
    float* bufAgg  = (float*)alloc((size_t)NN * D * 4);
    float* bufH    = (float*)alloc((size_t)NN * D * 4);  // layer-1 output
    int* cnt       = (int*)alloc((size_t)NN * 4);
    int* row_start = (int*)alloc((size_t)(NN + 1) * 4);
    int* cursor    = (int*)alloc((size_t)NN * 4);
    int* bsum      = (int*)alloc((size_t)SCAN_BLOCKS * 4);
    int* src_sorted= (int*)alloc((size_t)NE * 4);

    transpose6<<<dim3(64, 6), 256, 0, stream>>>(Wp1, Wl1, Wr1, Wp2, Wl2, Wr2,
                                                Wt[0], Wt[1], Wt[2], Wt[3], Wt[4], Wt[5]);

    // ---- CSR build (once; reused by both layers) ----
    hipMemsetAsync(cnt, 0, (size_t)NN * 4, stream);
    histogram<<<NE / 256, 256, 0, stream>>>(ei, cnt);
    scan_block<<<SCAN_BLOCKS, 256, 0, stream>>>(cnt, row_start, bsum);
    scan_sums<<<1, 256, 0, stream>>>(bsum);
    add_offsets<<<SCAN_BLOCKS, 256, 0, stream>>>(row_start, bsum, cursor);
    fill_csr<<<NE / 256, 256, 0, stream>>>(ei, cursor, src_sorted);

    const int GB = (NN + 31) / 32;   // gemm blocks
    const int GA = NN / 4;           // gather blocks (12500)

    // ---- layer 1 ----
    gemm128<<<GB, 256, 0, stream>>>(x, Wt[0], bp1, bufA, 0, 1);     // h1 = relu(x@Wp1.T+bp1)
    gather_mean<<<GA, 256, 0, stream>>>(bufA, row_start, src_sorted, bufAgg);
    gemm128<<<GB, 256, 0, stream>>>(bufAgg, Wt[1], bl1, bufH, 0, 0);  // z = mean@Wl1.T+bl1
    gemm128<<<GB, 256, 0, stream>>>(x, Wt[2], nullptr, bufH, 1, 1);   // h = relu(z + x@Wr1.T)

    // ---- layer 2 ----
    gemm128<<<GB, 256, 0, stream>>>(bufH, Wt[3], bp2, bufA, 0, 1);    // h2 = relu(h@Wp2.T+bp2)
    gather_mean<<<GA, 256, 0, stream>>>(bufA, row_start, src_sorted, bufAgg);
    gemm128<<<GB, 256, 0, stream>>>(bufAgg, Wt[4], bl2, out, 0, 0);   // out = mean@Wl2.T+bl2
    gemm128<<<GB, 256, 0, stream>>>(bufH, Wt[5], nullptr, out, 1, 0); // out += h@Wr2.T
}

// Round 3
// 427.315 us; speedup vs baseline: 3.7424x; 2.5890x over previous
//
#include <hip/hip_runtime.h>

#define NN 50000
#define NE 800000
#define D 128
#define SCAN_BLOCKS 196  // ceil(50000/256)

typedef __attribute__((ext_vector_type(8))) short bf16x8;
typedef __attribute__((ext_vector_type(4))) float f32x4;

__device__ inline unsigned short f2bf(float f) {
    union { float f; unsigned u; } v; v.f = f;
    unsigned r = v.u + 0x7FFF + ((v.u >> 16) & 1);  // RNE
    return (unsigned short)(r >> 16);
}
__device__ inline float bf2f(unsigned b) {
    union { unsigned u; float f; } v; v.u = b << 16;
    return v.f;
}

// ---------------- dtype conversion ----------------
__global__ __launch_bounds__(256)
void conv_f32_bf16(const float* __restrict__ in, unsigned short* __restrict__ out) {
    int i = blockIdx.x * 256 + threadIdx.x;  // float4 index
    float4 v = ((const float4*)in)[i];
    ushort4 o = {f2bf(v.x), f2bf(v.y), f2bf(v.z), f2bf(v.w)};
    ((ushort4*)out)[i] = o;
}

// ---------------- CSR build ----------------
__global__ __launch_bounds__(256)
void histogram(const int* __restrict__ ei, int* __restrict__ cnt) {
    int e = blockIdx.x * 256 + threadIdx.x;
    atomicAdd(&cnt[ei[NE + e]], 1);
}

__global__ __launch_bounds__(256)
void scan_block(const int* __restrict__ cnt, int* __restrict__ row_start,
                int* __restrict__ bsum) {
    __shared__ int tmp[256];
    int i = blockIdx.x * 256 + threadIdx.x;
    int v = (i < NN) ? cnt[i] : 0;
    tmp[threadIdx.x] = v;
    __syncthreads();
    for (int off = 1; off < 256; off <<= 1) {
        int t = (threadIdx.x >= off) ? tmp[threadIdx.x - off] : 0;
        __syncthreads();
        tmp[threadIdx.x] += t;
        __syncthreads();
    }
    if (i < NN) row_start[i] = tmp[threadIdx.x] - v;  // exclusive
    if (threadIdx.x == 255) bsum[blockIdx.x] = tmp[255];
}

__global__ __launch_bounds__(256)
void scan_sums(int* __restrict__ bsum) {
    __shared__ int tmp[256];
    int v = (threadIdx.x < SCAN_BLOCKS) ? bsum[threadIdx.x] : 0;
    tmp[threadIdx.x] = v;
    __syncthreads();
    for (int off = 1; off < 256; off <<= 1) {
        int t = (threadIdx.x >= off) ? tmp[threadIdx.x - off] : 0;
        __syncthreads();
        tmp[threadIdx.x] += t;
        __syncthreads();
    }
    if (threadIdx.x < SCAN_BLOCKS) bsum[threadIdx.x] = tmp[threadIdx.x] - v;
}

__global__ __launch_bounds__(256)
void add_offsets(int* __restrict__ row_start, const int* __restrict__ bsum,
                 int* __restrict__ cursor) {
    int i = blockIdx.x * 256 + threadIdx.x;
    if (i < NN) {
        int v = row_start[i] + bsum[blockIdx.x];
        row_start[i] = v;
        cursor[i] = v;
    } else if (i == NN) {
        row_start[NN] = NE;
    }
}

__global__ __launch_bounds__(256)
void fill_csr(const int* __restrict__ ei, int* __restrict__ cursor,
              int* __restrict__ src_sorted) {
    int e = blockIdx.x * 256 + threadIdx.x;
    int src = ei[e];
    int dst = ei[NE + e];
    int pos = atomicAdd(&cursor[dst], 1);
    src_sorted[pos] = src;
}

// ---------------- aggregation (bf16): one wave per dst node ----------------
// lane f handles features {2f, 2f+1} as one packed u32; full 256 B row per wave.
__global__ __launch_bounds__(256)
void gather_mean_bf16(const unsigned* __restrict__ h32,
                      const int* __restrict__ row_start,
                      const int* __restrict__ src_sorted,
                      unsigned* __restrict__ agg32) {
    const int n = blockIdx.x * 4 + (threadIdx.x >> 6);
    const int f = threadIdx.x & 63;
    const int b = row_start[n];
    const int e = row_start[n + 1];
    float sx = 0.0f, sy = 0.0f;
    for (int i = b; i < e; ++i) {
        const int s = src_sorted[i];
        const unsigned u = h32[s * 64 + f];
        sx += bf2f(u & 0xffffu);
        sy += bf2f(u >> 16);
    }
    const int deg = e - b;
    const float inv = 1.0f / (float)(deg > 0 ? deg : 1);
    agg32[n * 64 + f] =
        (unsigned)f2bf(sx * inv) | ((unsigned)f2bf(sy * inv) << 16);
}

// ---------------- bf16 MFMA GEMM ----------------
// out[n][c] = dot(A1[n,:],W1[c,:]) (+ dot(A2[n,:],W2[c,:])) + bias[c], opt relu.
// A,W row-major bf16. Both MFMA operands are [16 rows][k: quad*8+j] ->
// 16B contiguous loads; no LDS. Block: 128 rows x 128 cols, 4 waves.
template <typename OUTT>
__global__ __launch_bounds__(256)
void mfma_gemm(const unsigned short* __restrict__ A1,
               const unsigned short* __restrict__ W1,
               const unsigned short* __restrict__ A2,
               const unsigned short* __restrict__ W2,
               const float* __restrict__ bias, OUTT* __restrict__ out,
               int do_relu) {
    const int lane = threadIdx.x & 63;
    const int wave = threadIdx.x >> 6;
    const int quad = lane >> 4;
    const int l16 = lane & 15;
    const int rowBase = blockIdx.x * 128 + wave * 32;

    f32x4 acc[2][8];
#pragma unroll
    for (int mi = 0; mi < 2; ++mi)
#pragma unroll
        for (int ni = 0; ni < 8; ++ni) acc[mi][ni] = (f32x4){0.f, 0.f, 0.f, 0.f};

    int arow[2];
#pragma unroll
    for (int mi = 0; mi < 2; ++mi) {
        int r = rowBase + mi * 16 + l16;
        arow[mi] = (r < NN ? r : NN - 1) * D;  // clamp loads; stores guarded
    }

    const unsigned short* Ap[2] = {A1, A2};
    const unsigned short* Wp[2] = {W1, W2};
    for (int p = 0; p < 2; ++p) {
        const unsigned short* A = Ap[p];
        const unsigned short* W = Wp[p];
        if (!A) break;
#pragma unroll
        for (int kt = 0; kt < 4; ++kt) {
            const int ko = kt * 32 + quad * 8;
            bf16x8 a0 = *(const bf16x8*)&A[arow[0] + ko];
            bf16x8 a1 = *(const bf16x8*)&A[arow[1] + ko];
#pragma unroll
            for (int ni = 0; ni < 8; ++ni) {
                bf16x8 b = *(const bf16x8*)&W[(ni * 16 + l16) * D + ko];
                acc[0][ni] = __builtin_amdgcn_mfma_f32_16x16x32_bf16(a0, b, acc[0][ni], 0, 0, 0);
                acc[1][ni] = __builtin_amdgcn_mfma_f32_16x16x32_bf16(a1, b, acc[1][ni], 0, 0, 0);
            }
        }
    }

    float bv[8];
#pragma unroll
    for (int ni = 0; ni < 8; ++ni) bv[ni] = bias[ni * 16 + l16];

#pragma unroll
    for (int mi = 0; mi < 2; ++mi) {
#pragma unroll
        for (int r = 0; r < 4; ++r) {
            const int row = rowBase + mi * 16 + quad * 4 + r;
            if (row < NN) {
#pragma unroll
                for (int ni = 0; ni < 8; ++ni) {
                    float v = acc[mi][ni][r] + bv[ni];
                    if (do_relu) v = v > 0.f ? v : 0.f;
                    const int c = ni * 16 + l16;
                    if constexpr (sizeof(OUTT) == 2)
                        out[row * D + c] = (OUTT)f2bf(v);
                    else
                        out[row * D + c] = (OUTT)v;
                }
            }
        }
    }
}

extern "C" void kernel_launch(void* const* d_in, const int* in_sizes, int n_in,
                              void* d_out, int out_size, void* d_ws, size_t ws_size,
                              hipStream_t stream) {
    const float* x   = (const float*)d_in[0];
    const int*   ei  = (const int*)d_in[1];
    const float* Wp1 = (const float*)d_in[2];
    const float* bp1 = (const float*)d_in[3];
    const float* Wl1 = (const float*)d_in[4];
    const float* bl1 = (const float*)d_in[5];
    const float* Wr1 = (const float*)d_in[6];
    const float* Wp2 = (const float*)d_in[7];
    const float* bp2 = (const float*)d_in[8];
    const float* Wl2 = (const float*)d_in[9];
    const float* bl2 = (const float*)d_in[10];
    const float* Wr2 = (const float*)d_in[11];
    float* out = (float*)d_out;

    char* ws = (char*)d_ws;
    size_t off = 0;
    auto alloc = [&](size_t bytes) {
        void* p = ws + off;
        off += (bytes + 511) & ~511ull;
        return p;
    };
    unsigned short* Wb[6];
    for (int i = 0; i < 6; ++i) Wb[i] = (unsigned short*)alloc((size_t)D * D * 2);
    unsigned short* xb    = (unsigned short*)alloc((size_t)NN * D * 2);
    unsigned short* bufP  = (unsigned short*)alloc((size_t)NN * D * 2);  // projected h
    unsigned short* bufAg = (unsigned short*)alloc((size_t)NN * D * 2);  // aggregated
    unsigned short* bufH  = (unsigned short*)alloc((size_t)NN * D * 2);  // layer-1 out
    int* cnt        = (int*)alloc((size_t)NN * 4);
    int* row_start  = (int*)alloc((size_t)(NN + 1) * 4);
    int* cursor     = (int*)alloc((size_t)NN * 4);
    int* bsum       = (int*)alloc((size_t)SCAN_BLOCKS * 4);
    int* src_sorted = (int*)alloc((size_t)NE * 4);

    // ---- conversions ----
    const float* Wsrc[6] = {Wp1, Wl1, Wr1, Wp2, Wl2, Wr2};
    for (int i = 0; i < 6; ++i)
        conv_f32_bf16<<<D * D / 4 / 256, 256, 0, stream>>>(Wsrc[i], Wb[i]);
    conv_f32_bf16<<<NN * D / 4 / 256, 256, 0, stream>>>(x, xb);

    // ---- CSR build (once; reused by both layers) ----
    hipMemsetAsync(cnt, 0, (size_t)NN * 4, stream);
    histogram<<<NE / 256, 256, 0, stream>>>(ei, cnt);
    scan_block<<<SCAN_BLOCKS, 256, 0, stream>>>(cnt, row_start, bsum);
    scan_sums<<<1, 256, 0, stream>>>(bsum);
    add_offsets<<<SCAN_BLOCKS, 256, 0, stream>>>(row_start, bsum, cursor);
    fill_csr<<<NE / 256, 256, 0, stream>>>(ei, cursor, src_sorted);

    const int GG = (NN + 127) / 128;  // 391 gemm blocks
    const int GA = NN / 4;            // 12500 gather blocks

    // ---- layer 1 ----
    mfma_gemm<unsigned short><<<GG, 256, 0, stream>>>(
        xb, Wb[0], nullptr, nullptr, bp1, bufP, 1);            // relu(x@Wp1.T+bp1)
    gather_mean_bf16<<<GA, 256, 0, stream>>>(
        (const unsigned*)bufP, row_start, src_sorted, (unsigned*)bufAg);
    mfma_gemm<unsigned short><<<GG, 256, 0, stream>>>(
        bufAg, Wb[1], xb, Wb[2], bl1, bufH, 1);                // relu(agg@Wl1.T + x@Wr1.T + bl1)

    // ---- layer 2 ----
    mfma_gemm<unsigned short><<<GG, 256, 0, stream>>>(
        bufH, Wb[3], nullptr, nullptr, bp2, bufP, 1);          // relu(h@Wp2.T+bp2)
    gather_mean_bf16<<<GA, 256, 0, stream>>>(
        (const unsigned*)bufP, row_start, src_sorted, (unsigned*)bufAg);
    mfma_gemm<float><<<GG, 256, 0, stream>>>(
        bufAg, Wb[4], bufH, Wb[5], bl2, out, 0);               // agg@Wl2.T + h@Wr2.T + bl2
}

// Round 4
// 380.046 us; speedup vs baseline: 4.2078x; 1.1244x over previous
//
#include <hip/hip_runtime.h>

#define NN 50000
#define NE 800000
#define D 128
#define SCAN_BLOCKS 196  // ceil(50000/256)

typedef __attribute__((ext_vector_type(8))) short bf16x8;
typedef __attribute__((ext_vector_type(4))) float f32x4;

__device__ inline unsigned short f2bf(float f) {
    union { float f; unsigned u; } v; v.f = f;
    unsigned r = v.u + 0x7FFF + ((v.u >> 16) & 1);  // RNE
    return (unsigned short)(r >> 16);
}
__device__ inline float bf2f(unsigned b) {
    union { unsigned u; float f; } v; v.u = b << 16;
    return v.f;
}

// ---------------- dtype conversion ----------------
__global__ __launch_bounds__(256)
void conv_f32_bf16(const float* __restrict__ in, unsigned short* __restrict__ out) {
    int i = blockIdx.x * 256 + threadIdx.x;  // float4 index
    float4 v = ((const float4*)in)[i];
    ushort4 o = {f2bf(v.x), f2bf(v.y), f2bf(v.z), f2bf(v.w)};
    ((ushort4*)out)[i] = o;
}

// ---------------- CSR build ----------------
__global__ __launch_bounds__(256)
void histogram(const int* __restrict__ ei, int* __restrict__ cnt) {
    int e = blockIdx.x * 256 + threadIdx.x;
    atomicAdd(&cnt[ei[NE + e]], 1);
}

__global__ __launch_bounds__(256)
void scan_block(const int* __restrict__ cnt, int* __restrict__ row_start,
                int* __restrict__ bsum) {
    __shared__ int tmp[256];
    int i = blockIdx.x * 256 + threadIdx.x;
    int v = (i < NN) ? cnt[i] : 0;
    tmp[threadIdx.x] = v;
    __syncthreads();
    for (int off = 1; off < 256; off <<= 1) {
        int t = (threadIdx.x >= off) ? tmp[threadIdx.x - off] : 0;
        __syncthreads();
        tmp[threadIdx.x] += t;
        __syncthreads();
    }
    if (i < NN) row_start[i] = tmp[threadIdx.x] - v;  // exclusive
    if (threadIdx.x == 255) bsum[blockIdx.x] = tmp[255];
}

__global__ __launch_bounds__(256)
void scan_sums(int* __restrict__ bsum) {
    __shared__ int tmp[256];
    int v = (threadIdx.x < SCAN_BLOCKS) ? bsum[threadIdx.x] : 0;
    tmp[threadIdx.x] = v;
    __syncthreads();
    for (int off = 1; off < 256; off <<= 1) {
        int t = (threadIdx.x >= off) ? tmp[threadIdx.x - off] : 0;
        __syncthreads();
        tmp[threadIdx.x] += t;
        __syncthreads();
    }
    if (threadIdx.x < SCAN_BLOCKS) bsum[threadIdx.x] = tmp[threadIdx.x] - v;
}

__global__ __launch_bounds__(256)
void add_offsets(int* __restrict__ row_start, const int* __restrict__ bsum,
                 int* __restrict__ cursor) {
    int i = blockIdx.x * 256 + threadIdx.x;
    if (i < NN) {
        int v = row_start[i] + bsum[blockIdx.x];
        row_start[i] = v;
        cursor[i] = v;
    } else if (i == NN) {
        row_start[NN] = NE;
    }
}

__global__ __launch_bounds__(256)
void fill_csr(const int* __restrict__ ei, int* __restrict__ cursor,
              int* __restrict__ src_sorted) {
    int e = blockIdx.x * 256 + threadIdx.x;
    int src = ei[e];
    int dst = ei[NE + e];
    int pos = atomicAdd(&cursor[dst], 1);
    src_sorted[pos] = src;
}

// ---------------- aggregation (bf16): one wave per dst node ----------------
// lane f handles features {2f, 2f+1} packed in one u32. 8x unrolled so 8
// independent row-gathers are in flight per wave (latency-bound kernel).
__global__ __launch_bounds__(256)
void gather_mean_bf16(const unsigned* __restrict__ h32,
                      const int* __restrict__ row_start,
                      const int* __restrict__ src_sorted,
                      unsigned* __restrict__ agg32) {
    const int n = blockIdx.x * 4 + (threadIdx.x >> 6);
    const int f = threadIdx.x & 63;
    const int b = row_start[n];
    const int e = row_start[n + 1];
    float sx = 0.0f, sy = 0.0f;
    int i = b;
    for (; i + 8 <= e; i += 8) {
        int s0 = src_sorted[i + 0], s1 = src_sorted[i + 1];
        int s2 = src_sorted[i + 2], s3 = src_sorted[i + 3];
        int s4 = src_sorted[i + 4], s5 = src_sorted[i + 5];
        int s6 = src_sorted[i + 6], s7 = src_sorted[i + 7];
        unsigned u0 = h32[s0 * 64 + f], u1 = h32[s1 * 64 + f];
        unsigned u2 = h32[s2 * 64 + f], u3 = h32[s3 * 64 + f];
        unsigned u4 = h32[s4 * 64 + f], u5 = h32[s5 * 64 + f];
        unsigned u6 = h32[s6 * 64 + f], u7 = h32[s7 * 64 + f];
        sx += bf2f(u0 & 0xffffu) + bf2f(u1 & 0xffffu) + bf2f(u2 & 0xffffu) +
              bf2f(u3 & 0xffffu) + bf2f(u4 & 0xffffu) + bf2f(u5 & 0xffffu) +
              bf2f(u6 & 0xffffu) + bf2f(u7 & 0xffffu);
        sy += bf2f(u0 >> 16) + bf2f(u1 >> 16) + bf2f(u2 >> 16) +
              bf2f(u3 >> 16) + bf2f(u4 >> 16) + bf2f(u5 >> 16) +
              bf2f(u6 >> 16) + bf2f(u7 >> 16);
    }
    for (; i + 2 <= e; i += 2) {
        int s0 = src_sorted[i + 0], s1 = src_sorted[i + 1];
        unsigned u0 = h32[s0 * 64 + f], u1 = h32[s1 * 64 + f];
        sx += bf2f(u0 & 0xffffu) + bf2f(u1 & 0xffffu);
        sy += bf2f(u0 >> 16) + bf2f(u1 >> 16);
    }
    for (; i < e; ++i) {
        unsigned u = h32[src_sorted[i] * 64 + f];
        sx += bf2f(u & 0xffffu);
        sy += bf2f(u >> 16);
    }
    const int deg = e - b;
    const float inv = 1.0f / (float)(deg > 0 ? deg : 1);
    agg32[n * 64 + f] =
        (unsigned)f2bf(sx * inv) | ((unsigned)f2bf(sy * inv) << 16);
}

// ---------------- bf16 MFMA GEMM ----------------
// out[n][c] = dot(A1[n,:],W1[c,:]) (+ dot(A2[n,:],W2[c,:])) + bias[c], opt relu.
// A,W row-major bf16; fragments are direct 16B global loads, no LDS.
// Block: 64 rows x 128 cols, 4 waves (wave = 16 rows x 128 cols).
template <typename OUTT>
__global__ __launch_bounds__(256)
void mfma_gemm(const unsigned short* __restrict__ A1,
               const unsigned short* __restrict__ W1,
               const unsigned short* __restrict__ A2,
               const unsigned short* __restrict__ W2,
               const float* __restrict__ bias, OUTT* __restrict__ out,
               int do_relu) {
    const int lane = threadIdx.x & 63;
    const int wave = threadIdx.x >> 6;
    const int quad = lane >> 4;
    const int l16 = lane & 15;
    const int rowBase = blockIdx.x * 64 + wave * 16;

    f32x4 acc[8];
#pragma unroll
    for (int ni = 0; ni < 8; ++ni) acc[ni] = (f32x4){0.f, 0.f, 0.f, 0.f};

    int r = rowBase + l16;
    const int arow = (r < NN ? r : NN - 1) * D;  // clamp loads; stores guarded

    const unsigned short* Ap[2] = {A1, A2};
    const unsigned short* Wp[2] = {W1, W2};
    for (int p = 0; p < 2; ++p) {
        const unsigned short* A = Ap[p];
        const unsigned short* W = Wp[p];
        if (!A) break;
#pragma unroll
        for (int kt = 0; kt < 4; ++kt) {
            const int ko = kt * 32 + quad * 8;
            bf16x8 a0 = *(const bf16x8*)&A[arow + ko];
#pragma unroll
            for (int ni = 0; ni < 8; ++ni) {
                bf16x8 b = *(const bf16x8*)&W[(ni * 16 + l16) * D + ko];
                acc[ni] = __builtin_amdgcn_mfma_f32_16x16x32_bf16(a0, b, acc[ni], 0, 0, 0);
            }
        }
    }

    float bv[8];
#pragma unroll
    for (int ni = 0; ni < 8; ++ni) bv[ni] = bias[ni * 16 + l16];

#pragma unroll
    for (int rr = 0; rr < 4; ++rr) {
        const int row = rowBase + quad * 4 + rr;
        if (row < NN) {
#pragma unroll
            for (int ni = 0; ni < 8; ++ni) {
                float v = acc[ni][rr] + bv[ni];
                if (do_relu) v = v > 0.f ? v : 0.f;
                const int c = ni * 16 + l16;
                if constexpr (sizeof(OUTT) == 2)
                    out[row * D + c] = (OUTT)f2bf(v);
                else
                    out[row * D + c] = (OUTT)v;
            }
        }
    }
}

extern "C" void kernel_launch(void* const* d_in, const int* in_sizes, int n_in,
                              void* d_out, int out_size, void* d_ws, size_t ws_size,
                              hipStream_t stream) {
    const float* x   = (const float*)d_in[0];
    const int*   ei  = (const int*)d_in[1];
    const float* Wp1 = (const float*)d_in[2];
    const float* bp1 = (const float*)d_in[3];
    const float* Wl1 = (const float*)d_in[4];
    const float* bl1 = (const float*)d_in[5];
    const float* Wr1 = (const float*)d_in[6];
    const float* Wp2 = (const float*)d_in[7];
    const float* bp2 = (const float*)d_in[8];
    const float* Wl2 = (const float*)d_in[9];
    const float* bl2 = (const float*)d_in[10];
    const float* Wr2 = (const float*)d_in[11];
    float* out = (float*)d_out;

    char* ws = (char*)d_ws;
    size_t off = 0;
    auto alloc = [&](size_t bytes) {
        void* p = ws + off;
        off += (bytes + 511) & ~511ull;
        return p;
    };
    unsigned short* Wb[6];
    for (int i = 0; i < 6; ++i) Wb[i] = (unsigned short*)alloc((size_t)D * D * 2);
    unsigned short* xb    = (unsigned short*)alloc((size_t)NN * D * 2);
    unsigned short* bufP  = (unsigned short*)alloc((size_t)NN * D * 2);  // projected h
    unsigned short* bufAg = (unsigned short*)alloc((size_t)NN * D * 2);  // aggregated
    unsigned short* bufH  = (unsigned short*)alloc((size_t)NN * D * 2);  // layer-1 out
    int* cnt        = (int*)alloc((size_t)NN * 4);
    int* row_start  = (int*)alloc((size_t)(NN + 1) * 4);
    int* cursor     = (int*)alloc((size_t)NN * 4);
    int* bsum       = (int*)alloc((size_t)SCAN_BLOCKS * 4);
    int* src_sorted = (int*)alloc((size_t)NE * 4);

    // ---- conversions ----
    const float* Wsrc[6] = {Wp1, Wl1, Wr1, Wp2, Wl2, Wr2};
    for (int i = 0; i < 6; ++i)
        conv_f32_bf16<<<D * D / 4 / 256, 256, 0, stream>>>(Wsrc[i], Wb[i]);
    conv_f32_bf16<<<NN * D / 4 / 256, 256, 0, stream>>>(x, xb);

    // ---- CSR build (once; reused by both layers) ----
    hipMemsetAsync(cnt, 0, (size_t)NN * 4, stream);
    histogram<<<NE / 256, 256, 0, stream>>>(ei, cnt);
    scan_block<<<SCAN_BLOCKS, 256, 0, stream>>>(cnt, row_start, bsum);
    scan_sums<<<1, 256, 0, stream>>>(bsum);
    add_offsets<<<SCAN_BLOCKS, 256, 0, stream>>>(row_start, bsum, cursor);
    fill_csr<<<NE / 256, 256, 0, stream>>>(ei, cursor, src_sorted);

    const int GG = (NN + 63) / 64;   // 782 gemm blocks
    const int GA = NN / 4;           // 12500 gather blocks

    // ---- layer 1 ----
    mfma_gemm<unsigned short><<<GG, 256, 0, stream>>>(
        xb, Wb[0], nullptr, nullptr, bp1, bufP, 1);            // relu(x@Wp1.T+bp1)
    gather_mean_bf16<<<GA, 256, 0, stream>>>(
        (const unsigned*)bufP, row_start, src_sorted, (unsigned*)bufAg);
    mfma_gemm<unsigned short><<<GG, 256, 0, stream>>>(
        bufAg, Wb[1], xb, Wb[2], bl1, bufH, 1);                // relu(agg@Wl1.T + x@Wr1.T + bl1)

    // ---- layer 2 ----
    mfma_gemm<unsigned short><<<GG, 256, 0, stream>>>(
        bufH, Wb[3], nullptr, nullptr, bp2, bufP, 1);          // relu(h@Wp2.T+bp2)
    gather_mean_bf16<<<GA, 256, 0, stream>>>(
        (const unsigned*)bufP, row_start, src_sorted, (unsigned*)bufAg);
    mfma_gemm<float><<<GG, 256, 0, stream>>>(
        bufAg, Wb[4], bufH, Wb[5], bl2, out, 0);               // agg@Wl2.T + h@Wr2.T + bl2
}